// Round 9
// baseline (562.704 us; speedup 1.0000x reference)
//
#include <hip/hip_runtime.h>
#include <math.h>

#define NN   20000
#define NE   320000
#define NH   4
#define NREL 40
#define FIN  768
#define HIDD 128
#define NCLS 9
#define MAXDEG 128

// k_prep index ranges: casts then tables
#define XCAST4   3840000
#define B0_END   4233216
#define BM_END   4429824
#define PREP_END (BM_END + 10112)

typedef __attribute__((ext_vector_type(8))) short short8;
typedef __attribute__((ext_vector_type(4))) float f32x4;
typedef unsigned short b16;

__device__ __forceinline__ float lrelu(float v, float s) { return v > 0.f ? v : v * s; }
__device__ __forceinline__ b16 f2b(float f) {
    unsigned int u = __float_as_uint(f);
    unsigned int r = u + 0x7FFFu + ((u >> 16) & 1u);
    return (b16)(r >> 16);
}
__device__ __forceinline__ float b2f(b16 u) { return __uint_as_float(((unsigned int)u) << 16); }

// ---------------- init: zero counts + all 4 BN sum slots ----------------
__global__ void k_init(int* __restrict__ counts, float* __restrict__ sums) {
    int i = blockIdx.x * blockDim.x + threadIdx.x;
    if (i < NN) counts[i] = 0;
    if (i < 1024) sums[i] = 0.f;
}

// ---------------- CSR build ----------------
__global__ void k_count(const int* __restrict__ dst, int* __restrict__ counts) {
    int e = blockIdx.x * blockDim.x + threadIdx.x;
    if (e < NE) atomicAdd(&counts[dst[e]], 1);
}
__global__ void k_scan(const int* __restrict__ counts, int* __restrict__ rowptr,
                       int* __restrict__ cursor) {
    __shared__ int sh[1024];
    int t = threadIdx.x;
    int base = t * 20;
    int sum = 0;
    if (t < 1000) for (int k = 0; k < 20; ++k) sum += counts[base + k];
    sh[t] = sum;
    __syncthreads();
    for (int off = 1; off < 1024; off <<= 1) {
        int v = (t >= off) ? sh[t - off] : 0;
        __syncthreads();
        sh[t] += v;
        __syncthreads();
    }
    int ex = (t == 0) ? 0 : sh[t - 1];
    if (t == 0) { rowptr[0] = 0; cursor[0] = 0; }
    if (t < 1000) {
        int run = ex;
        for (int k = 0; k < 20; ++k) {
            run += counts[base + k];
            rowptr[base + k + 1] = run;
            cursor[base + k + 1] = run;
        }
    }
}
__global__ void k_fill(const int* __restrict__ dst, int* __restrict__ cursor, int* __restrict__ eidx) {
    int e = blockIdx.x * blockDim.x + threadIdx.x;
    if (e < NE) {
        int pos = atomicAdd(&cursor[dst[e]], 1);
        eidx[pos] = e;
    }
}
__global__ void k_permute(const int* __restrict__ eidx, const int* __restrict__ src,
                          const int* __restrict__ etype, const int* __restrict__ dist,
                          int* __restrict__ srcp, int* __restrict__ etp,
                          float* __restrict__ distwp) {
    int p = blockIdx.x * blockDim.x + threadIdx.x;
    if (p >= NE) return;
    int e = eidx[p];
    srcp[p] = src[e];
    etp[p] = etype[e];
    distwp[p] = 1.f / (1.f + (float)dist[e]);
}

// ---------------- fused prep: casts + small tables ----------------
__global__ void k_prep(const float* __restrict__ x, const float* __restrict__ W0,
                       const float* __restrict__ Wm, b16* __restrict__ xb,
                       b16* __restrict__ B0t, b16* __restrict__ Bmt,
                       const float* __restrict__ rel0, const float* __restrict__ relm,
                       const float* __restrict__ relL, const float* __restrict__ ae0,
                       const float* __restrict__ aem, const float* __restrict__ aeL,
                       const float* __restrict__ asrcm, const float* __restrict__ adstm,
                       const float* __restrict__ WL, const float* __restrict__ asrcL,
                       const float* __restrict__ adstL,
                       float* __restrict__ etab, float* __restrict__ wsm,
                       float* __restrict__ wdm, b16* __restrict__ WLt,
                       float* __restrict__ aS48, float* __restrict__ aD48) {
    int id = blockIdx.x * blockDim.x + threadIdx.x;
    if (id < XCAST4) {
        float4 v = ((const float4*)x)[id];
        ushort4 o;
        o.x = f2b(v.x); o.y = f2b(v.y); o.z = f2b(v.z); o.w = f2b(v.w);
        ((ushort4*)xb)[id] = o;
    } else if (id < B0_END) {
        int i = id - XCAST4;
        int c = i / FIN, k = i % FIN;
        int h = c >> 7, o = c & 127;
        B0t[i] = f2b(W0[((size_t)h * FIN + k) * HIDD + o]);
    } else if (id < BM_END) {
        int i = id - B0_END;
        int l = i / (HIDD * 512);
        int r = i % (HIDD * 512);
        int o = r / 512, hf = r % 512;
        Bmt[i] = f2b(Wm[(size_t)l * 512 * HIDD + (size_t)hf * HIDD + o]);
    } else if (id < PREP_END) {
        int id0 = id - BM_END;
        if (id0 < 800) {
            int tab = id0 / (NREL * NH);
            int rem = id0 % (NREL * NH);
            int t = rem >> 2, h = rem & 3;
            const float *rel, *ae;
            if (tab == 0)      { rel = rel0;                        ae = ae0; }
            else if (tab <= 3) { rel = relm + (tab - 1) * NREL * 2; ae = aem + (tab - 1) * NH * 2; }
            else               { rel = relL;                        ae = aeL; }
            etab[id0] = rel[t * 2] * ae[h * 2] + rel[t * 2 + 1] * ae[h * 2 + 1];
        } else if (id0 < 3872) {
            int id2 = id0 - 800;
            int which = id2 / 1536;
            int r = id2 % 1536;
            int ih = r / HIDD;
            int f = r % HIDD;
            const float* w = Wm + ((size_t)ih * HIDD + f) * HIDD;
            const float* a = (which ? adstm : asrcm) + ih * HIDD;
            float acc = 0.f;
            for (int o = 0; o < HIDD; ++o) acc += w[o] * a[o];
            (which ? wdm : wsm)[r] = acc;
        } else if (id0 < 10016) {
            int id3 = id0 - 3872;
            int cf = id3 / HIDD, k = id3 % HIDD;
            float v = 0.f;
            if (cf < 36) {
                int h = cf / 9, c = cf % 9;
                v = WL[((size_t)h * HIDD + k) * NCLS + c];
            }
            WLt[id3] = f2b(v);
        } else {
            int id4 = id0 - 10016;
            int c = id4 % 48;
            float v = (c < 36) ? ((id4 < 48) ? asrcL[c] : adstL[c]) : 0.f;
            if (id4 < 48) aS48[c] = v; else aD48[c] = v;
        }
    }
}

// ---------------- conv0 MFMA GEMM (bf16 out) + fused per-head scores ----------------
__global__ __launch_bounds__(256) void k_mfma_gemm(
    const b16* __restrict__ A, const b16* __restrict__ Bt, int M, int K, int N,
    b16* __restrict__ Cb, const float* __restrict__ asv, const float* __restrict__ adv,
    float* __restrict__ esp, float* __restrict__ edp) {
    __shared__ b16 As[128][40];
    __shared__ b16 Bs[128][40];
    __shared__ float sc_es[2][128];
    __shared__ float sc_ed[2][128];
    int tid = threadIdx.x;
    int lane = tid & 63, wave = tid >> 6;
    int wm = wave >> 1, wn = wave & 1;
    int l16 = lane & 15, quad = lane >> 4;
    int row0 = blockIdx.x * 128, col0 = blockIdx.y * 128;

    int c0 = tid, c1 = tid + 256;
    int ar0 = c0 >> 2, as0 = (c0 & 3) << 3;
    int ar1 = c1 >> 2, as1 = (c1 & 3) << 3;
    bool va0 = (row0 + ar0) < M, va1 = (row0 + ar1) < M;
    const b16* Ap0 = A + (size_t)(row0 + ar0) * K + as0;
    const b16* Ap1 = A + (size_t)(row0 + ar1) * K + as1;
    const b16* Bp0 = Bt + (size_t)(col0 + ar0) * K + as0;
    const b16* Bp1 = Bt + (size_t)(col0 + ar1) * K + as1;

    f32x4 acc[4][4];
#pragma unroll
    for (int i = 0; i < 4; ++i)
#pragma unroll
        for (int j = 0; j < 4; ++j) acc[i][j] = (f32x4){0.f, 0.f, 0.f, 0.f};
    short8 zz = {0, 0, 0, 0, 0, 0, 0, 0};

    for (int kt = 0; kt < K; kt += 32) {
        short8 a0 = va0 ? *(const short8*)(Ap0 + kt) : zz;
        short8 a1 = va1 ? *(const short8*)(Ap1 + kt) : zz;
        short8 b0 = *(const short8*)(Bp0 + kt);
        short8 b1 = *(const short8*)(Bp1 + kt);
        __syncthreads();
        *(short8*)&As[ar0][as0] = a0;
        *(short8*)&As[ar1][as1] = a1;
        *(short8*)&Bs[ar0][as0] = b0;
        *(short8*)&Bs[ar1][as1] = b1;
        __syncthreads();
        short8 bf[4];
#pragma unroll
        for (int ni = 0; ni < 4; ++ni)
            bf[ni] = *(const short8*)&Bs[wn * 64 + ni * 16 + l16][quad * 8];
#pragma unroll
        for (int mi = 0; mi < 4; ++mi) {
            short8 af = *(const short8*)&As[wm * 64 + mi * 16 + l16][quad * 8];
#pragma unroll
            for (int ni = 0; ni < 4; ++ni)
                acc[mi][ni] = __builtin_amdgcn_mfma_f32_16x16x32_bf16(af, bf[ni], acc[mi][ni], 0, 0, 0);
        }
    }
#pragma unroll
    for (int mi = 0; mi < 4; ++mi) {
        int rb = row0 + wm * 64 + mi * 16 + quad * 4;
#pragma unroll
        for (int ni = 0; ni < 4; ++ni) {
            int c = col0 + wn * 64 + ni * 16 + l16;
#pragma unroll
            for (int r = 0; r < 4; ++r) {
                int row = rb + r;
                if (row < M) Cb[(size_t)row * N + c] = f2b(acc[mi][ni][r]);
            }
        }
    }
    // fused scores: col-block == head
    {
        int h = blockIdx.y;
        float as_c[4], ad_c[4];
#pragma unroll
        for (int ni = 0; ni < 4; ++ni) {
            int c = wn * 64 + ni * 16 + l16;
            as_c[ni] = asv[h * 128 + c];
            ad_c[ni] = adv[h * 128 + c];
        }
#pragma unroll
        for (int mi = 0; mi < 4; ++mi) {
#pragma unroll
            for (int r = 0; r < 4; ++r) {
                float pes = 0.f, ped = 0.f;
#pragma unroll
                for (int ni = 0; ni < 4; ++ni) {
                    float v = acc[mi][ni][r];
                    pes += v * as_c[ni];
                    ped += v * ad_c[ni];
                }
#pragma unroll
                for (int m = 1; m < 16; m <<= 1) {
                    pes += __shfl_xor(pes, m, 64);
                    ped += __shfl_xor(ped, m, 64);
                }
                if (l16 == 0) {
                    int rl = wm * 64 + mi * 16 + quad * 4 + r;
                    sc_es[wn][rl] = pes;
                    sc_ed[wn][rl] = ped;
                }
            }
        }
        __syncthreads();
        if (tid < 128) {
            int row = row0 + tid;
            if (row < M) {
                esp[row * 4 + h] = sc_es[0][tid] + sc_es[1][tid];
                edp[row * 4 + h] = sc_ed[0][tid] + sc_ed[1][tid];
            }
        }
    }
}

// ---------------- mid MFMA GEMM 64x128 tile + fused BN stats ----------------
__global__ __launch_bounds__(128) void k_gemm_mid(
    const b16* __restrict__ A, const b16* __restrict__ Bt, float* __restrict__ Cf,
    const float* __restrict__ bias, const float* __restrict__ resid,
    float* __restrict__ sums) {
    __shared__ b16 As[64][40];
    __shared__ b16 Bs[128][40];
    int tid = threadIdx.x;
    int lane = tid & 63, wave = tid >> 6;  // wave = col-half
    int l16 = lane & 15, quad = lane >> 4;
    int row0 = blockIdx.x * 64;
    const int K = 512;

    int ar[2], asg[2]; bool av[2];
    const b16* Ap[2];
#pragma unroll
    for (int j = 0; j < 2; ++j) {
        int c = tid + j * 128;
        ar[j] = c >> 2; asg[j] = (c & 3) << 3;
        int grow = row0 + ar[j];
        av[j] = grow < NN;
        Ap[j] = A + (size_t)(av[j] ? grow : 0) * K + asg[j];
    }
    int br[4], bsg[4];
    const b16* Bp[4];
#pragma unroll
    for (int j = 0; j < 4; ++j) {
        int c = tid + j * 128;
        br[j] = c >> 2; bsg[j] = (c & 3) << 3;
        Bp[j] = Bt + (size_t)br[j] * K + bsg[j];
    }

    f32x4 acc[4][4];
#pragma unroll
    for (int i = 0; i < 4; ++i)
#pragma unroll
        for (int j = 0; j < 4; ++j) acc[i][j] = (f32x4){0.f, 0.f, 0.f, 0.f};
    short8 zz = {0, 0, 0, 0, 0, 0, 0, 0};

    for (int kt = 0; kt < K; kt += 32) {
        short8 a[2], b[4];
#pragma unroll
        for (int j = 0; j < 2; ++j) a[j] = av[j] ? *(const short8*)(Ap[j] + kt) : zz;
#pragma unroll
        for (int j = 0; j < 4; ++j) b[j] = *(const short8*)(Bp[j] + kt);
        __syncthreads();
#pragma unroll
        for (int j = 0; j < 2; ++j) *(short8*)&As[ar[j]][asg[j]] = a[j];
#pragma unroll
        for (int j = 0; j < 4; ++j) *(short8*)&Bs[br[j]][bsg[j]] = b[j];
        __syncthreads();
        short8 bf[4];
#pragma unroll
        for (int ni = 0; ni < 4; ++ni)
            bf[ni] = *(const short8*)&Bs[wave * 64 + ni * 16 + l16][quad * 8];
#pragma unroll
        for (int mi = 0; mi < 4; ++mi) {
            short8 af = *(const short8*)&As[mi * 16 + l16][quad * 8];
#pragma unroll
            for (int ni = 0; ni < 4; ++ni)
                acc[mi][ni] = __builtin_amdgcn_mfma_f32_16x16x32_bf16(af, bf[ni], acc[mi][ni], 0, 0, 0);
        }
    }
    float sp[4] = {0.f, 0.f, 0.f, 0.f}, qp[4] = {0.f, 0.f, 0.f, 0.f};
#pragma unroll
    for (int mi = 0; mi < 4; ++mi) {
        int rb = row0 + mi * 16 + quad * 4;
#pragma unroll
        for (int ni = 0; ni < 4; ++ni) {
            int c = wave * 64 + ni * 16 + l16;
#pragma unroll
            for (int r = 0; r < 4; ++r) {
                int row = rb + r;
                if (row < NN) {
                    float v = acc[mi][ni][r] * 0.25f + bias[c] + resid[(size_t)row * HIDD + c];
                    Cf[(size_t)row * HIDD + c] = v;
                    sp[ni] += v;
                    qp[ni] += v * v;
                }
            }
        }
    }
#pragma unroll
    for (int ni = 0; ni < 4; ++ni) {
        float s = sp[ni], q = qp[ni];
        s += __shfl_xor(s, 16, 64); s += __shfl_xor(s, 32, 64);
        q += __shfl_xor(q, 16, 64); q += __shfl_xor(q, 32, 64);
        if (quad == 0) {
            int c = wave * 64 + ni * 16 + l16;
            atomicAdd(&sums[c], s);
            atomicAdd(&sums[128 + c], q);
        }
    }
}

// ---------------- gemmL via MFMA + fused final scores ----------------
__global__ __launch_bounds__(256) void k_gemmL_mfma(
    const b16* __restrict__ hbb, const b16* __restrict__ WLt, float* __restrict__ hL,
    const float* __restrict__ aS48, const float* __restrict__ aD48,
    float* __restrict__ es, float* __restrict__ ed) {
    int tid = threadIdx.x;
    int lane = tid & 63, wave = tid >> 6;
    int l16 = lane & 15, quad = lane >> 4;
    int base = blockIdx.x * 64 + wave * 16;
    int na = base + l16;
    f32x4 acc[3];
#pragma unroll
    for (int ct = 0; ct < 3; ++ct) acc[ct] = (f32x4){0.f, 0.f, 0.f, 0.f};
    short8 zz = {0, 0, 0, 0, 0, 0, 0, 0};
#pragma unroll
    for (int k0 = 0; k0 < 128; k0 += 32) {
        short8 af = (na < NN) ? *(const short8*)(hbb + (size_t)na * HIDD + k0 + quad * 8) : zz;
#pragma unroll
        for (int ct = 0; ct < 3; ++ct) {
            short8 bf = *(const short8*)(WLt + (size_t)(ct * 16 + l16) * HIDD + k0 + quad * 8);
            acc[ct] = __builtin_amdgcn_mfma_f32_16x16x32_bf16(af, bf, acc[ct], 0, 0, 0);
        }
    }
#pragma unroll
    for (int ct = 0; ct < 3; ++ct) {
        int col = ct * 16 + l16;
        if (col < 36) {
#pragma unroll
            for (int r = 0; r < 4; ++r) {
                int row = base + quad * 4 + r;
                if (row < NN) hL[(size_t)row * 36 + col] = acc[ct][r];
            }
        }
    }
    // fused scores (cols padded >=36 have aS48=0)
    float asv[3], adv[3]; int hh[3];
#pragma unroll
    for (int ct = 0; ct < 3; ++ct) {
        int col = ct * 16 + l16;
        asv[ct] = aS48[col];
        adv[ct] = aD48[col];
        hh[ct] = (col < 36) ? (col / 9) : 0;
    }
#pragma unroll
    for (int r = 0; r < 4; ++r) {
        float pes[4] = {0.f, 0.f, 0.f, 0.f}, ped[4] = {0.f, 0.f, 0.f, 0.f};
#pragma unroll
        for (int ct = 0; ct < 3; ++ct) {
            float vs = acc[ct][r] * asv[ct];
            float vd = acc[ct][r] * adv[ct];
#pragma unroll
            for (int h = 0; h < 4; ++h) {
                pes[h] += (hh[ct] == h) ? vs : 0.f;
                ped[h] += (hh[ct] == h) ? vd : 0.f;
            }
        }
#pragma unroll
        for (int m = 1; m < 16; m <<= 1) {
#pragma unroll
            for (int h = 0; h < 4; ++h) {
                pes[h] += __shfl_xor(pes[h], m, 64);
                ped[h] += __shfl_xor(ped[h], m, 64);
            }
        }
        if (l16 == 0) {
            int row = base + quad * 4 + r;
            if (row < NN) {
#pragma unroll
                for (int h = 0; h < 4; ++h) {
                    es[row * 4 + h] = pes[h];
                    ed[row * 4 + h] = ped[h];
                }
            }
        }
    }
}

// ---------------- fused edge-softmax + aggregation ----------------
// conv0: gather bf16 h0 rows (512-wide, ushort4, half-block seg split)
__global__ __launch_bounds__(64) void k_agg0_f(
    const int* __restrict__ rowptr, const int* __restrict__ srcp,
    const int* __restrict__ etpp, const float* __restrict__ distwp,
    const float* __restrict__ es, const float* __restrict__ ed,
    const float* __restrict__ etab, const b16* __restrict__ h0b,
    const float* __restrict__ b0, float* __restrict__ xout) {
    __shared__ float4 exw[MAXDEG];
    __shared__ float comb[32][4];
    int n = blockIdx.x, t = threadIdx.x;
    int p0 = rowptr[n], p1 = rowptr[n + 1];
    int deg = p1 - p0;
    float4 edn = ((const float4*)ed)[n];
    float d0 = 0.f, d1 = 0.f, d2 = 0.f, d3 = 0.f;
    for (int p = p0 + t; p < p1; p += 64) {
        int s = srcp[p], ty = etpp[p];
        float w = distwp[p];
        float4 a = ((const float4*)es)[s];
        float4 c = ((const float4*)etab)[ty];
        float e0 = __expf(lrelu(a.x + edn.x + c.x, 0.2f));
        float e1 = __expf(lrelu(a.y + edn.y + c.y, 0.2f));
        float e2 = __expf(lrelu(a.z + edn.z + c.z, 0.2f));
        float e3 = __expf(lrelu(a.w + edn.w + c.w, 0.2f));
        d0 += e0; d1 += e1; d2 += e2; d3 += e3;
        int ix = p - p0;
        if (ix < MAXDEG) exw[ix] = make_float4(e0 * w, e1 * w, e2 * w, e3 * w);
    }
#pragma unroll
    for (int off = 32; off > 0; off >>= 1) {
        d0 += __shfl_down(d0, off, 64);
        d1 += __shfl_down(d1, off, 64);
        d2 += __shfl_down(d2, off, 64);
        d3 += __shfl_down(d3, off, 64);
    }
    d0 = __shfl(d0, 0, 64); d1 = __shfl(d1, 0, 64);
    d2 = __shfl(d2, 0, 64); d3 = __shfl(d3, 0, 64);
    float r0 = 1.f / (d0 + 1e-16f), r1 = 1.f / (d1 + 1e-16f);
    float r2 = 1.f / (d2 + 1e-16f), r3 = 1.f / (d3 + 1e-16f);
    __syncthreads();
    int half = t >> 5, q = t & 31;
    int cq = q * 4;
    float ra = half ? r2 : r0, rb = half ? r3 : r1;
    int sega = half * 256;  // head offset in elements
    float acc[4] = {0.f, 0.f, 0.f, 0.f};
    if (deg <= MAXDEG) {
        int p = p0;
        for (; p + 4 <= p1; p += 4) {
            int ss[4]; float4 ee[4];
#pragma unroll
            for (int j = 0; j < 4; ++j) { ss[j] = srcp[p + j]; ee[j] = exw[p - p0 + j]; }
#pragma unroll
            for (int j = 0; j < 4; ++j) {
                float ca = (half ? ee[j].z : ee[j].x) * ra;
                float cb = (half ? ee[j].w : ee[j].y) * rb;
                const b16* hr = h0b + (size_t)ss[j] * 512 + sega + cq;
                ushort4 ua = *(const ushort4*)(hr);
                ushort4 ub = *(const ushort4*)(hr + 128);
                acc[0] += ca * b2f(ua.x) + cb * b2f(ub.x);
                acc[1] += ca * b2f(ua.y) + cb * b2f(ub.y);
                acc[2] += ca * b2f(ua.z) + cb * b2f(ub.z);
                acc[3] += ca * b2f(ua.w) + cb * b2f(ub.w);
            }
        }
        for (; p < p1; ++p) {
            int s = srcp[p];
            float4 e = exw[p - p0];
            float ca = (half ? e.z : e.x) * ra;
            float cb = (half ? e.w : e.y) * rb;
            const b16* hr = h0b + (size_t)s * 512 + sega + cq;
            ushort4 ua = *(const ushort4*)(hr);
            ushort4 ub = *(const ushort4*)(hr + 128);
            acc[0] += ca * b2f(ua.x) + cb * b2f(ub.x);
            acc[1] += ca * b2f(ua.y) + cb * b2f(ub.y);
            acc[2] += ca * b2f(ua.z) + cb * b2f(ub.z);
            acc[3] += ca * b2f(ua.w) + cb * b2f(ub.w);
        }
    } else {
        for (int p = p0; p < p1; ++p) {
            int s = srcp[p];
            int ix = p - p0;
            float4 e;
            if (ix < MAXDEG) e = exw[ix];
            else {
                int ty = etpp[p];
                float w = distwp[p];
                float4 a = ((const float4*)es)[s];
                float4 c = ((const float4*)etab)[ty];
                e.x = __expf(lrelu(a.x + edn.x + c.x, 0.2f)) * w;
                e.y = __expf(lrelu(a.y + edn.y + c.y, 0.2f)) * w;
                e.z = __expf(lrelu(a.z + edn.z + c.z, 0.2f)) * w;
                e.w = __expf(lrelu(a.w + edn.w + c.w, 0.2f)) * w;
            }
            float ca = (half ? e.z : e.x) * ra;
            float cb = (half ? e.w : e.y) * rb;
            const b16* hr = h0b + (size_t)s * 512 + sega + cq;
            ushort4 ua = *(const ushort4*)(hr);
            ushort4 ub = *(const ushort4*)(hr + 128);
            acc[0] += ca * b2f(ua.x) + cb * b2f(ub.x);
            acc[1] += ca * b2f(ua.y) + cb * b2f(ub.y);
            acc[2] += ca * b2f(ua.z) + cb * b2f(ub.z);
            acc[3] += ca * b2f(ua.w) + cb * b2f(ub.w);
        }
    }
    if (half == 1) {
        comb[q][0] = acc[0]; comb[q][1] = acc[1];
        comb[q][2] = acc[2]; comb[q][3] = acc[3];
    }
    __syncthreads();
    if (half == 0) {
        float4 o;
        o.x = 0.25f * (acc[0] + comb[q][0]) + b0[cq];
        o.y = 0.25f * (acc[1] + comb[q][1]) + b0[cq + 1];
        o.z = 0.25f * (acc[2] + comb[q][2]) + b0[cq + 2];
        o.w = 0.25f * (acc[3] + comb[q][3]) + b0[cq + 3];
        *(float4*)(xout + (size_t)n * HIDD + cq) = o;
    }
}
// mid: gather bf16 hb rows (128-wide, ushort4, half-block edge split)
__global__ __launch_bounds__(64) void k_aggmid_f(
    const int* __restrict__ rowptr, const int* __restrict__ srcp,
    const int* __restrict__ etpp, const float* __restrict__ distwp,
    const float* __restrict__ es, const float* __restrict__ ed,
    const float* __restrict__ etab, const b16* __restrict__ hbb,
    b16* __restrict__ aggb) {
    __shared__ float4 exw[MAXDEG];
    __shared__ float comb[32][16];
    int n = blockIdx.x, t = threadIdx.x;
    int p0 = rowptr[n], p1 = rowptr[n + 1];
    int deg = p1 - p0;
    float4 edn = ((const float4*)ed)[n];
    float d0 = 0.f, d1 = 0.f, d2 = 0.f, d3 = 0.f;
    for (int p = p0 + t; p < p1; p += 64) {
        int s = srcp[p], ty = etpp[p];
        float w = distwp[p];
        float4 a = ((const float4*)es)[s];
        float4 c = ((const float4*)etab)[ty];
        float e0 = __expf(lrelu(a.x + edn.x + c.x, 0.2f));
        float e1 = __expf(lrelu(a.y + edn.y + c.y, 0.2f));
        float e2 = __expf(lrelu(a.z + edn.z + c.z, 0.2f));
        float e3 = __expf(lrelu(a.w + edn.w + c.w, 0.2f));
        d0 += e0; d1 += e1; d2 += e2; d3 += e3;
        int ix = p - p0;
        if (ix < MAXDEG) exw[ix] = make_float4(e0 * w, e1 * w, e2 * w, e3 * w);
    }
#pragma unroll
    for (int off = 32; off > 0; off >>= 1) {
        d0 += __shfl_down(d0, off, 64);
        d1 += __shfl_down(d1, off, 64);
        d2 += __shfl_down(d2, off, 64);
        d3 += __shfl_down(d3, off, 64);
    }
    d0 = __shfl(d0, 0, 64); d1 = __shfl(d1, 0, 64);
    d2 = __shfl(d2, 0, 64); d3 = __shfl(d3, 0, 64);
    float r0 = 1.f / (d0 + 1e-16f), r1 = 1.f / (d1 + 1e-16f);
    float r2 = 1.f / (d2 + 1e-16f), r3 = 1.f / (d3 + 1e-16f);
    __syncthreads();
    int half = t >> 5, q = t & 31;
    int cq = q * 4;
    float acc[4][4];
#pragma unroll
    for (int h = 0; h < 4; ++h)
#pragma unroll
        for (int j = 0; j < 4; ++j) acc[h][j] = 0.f;
    auto doE = [&](int s, float4 e) {
        float c0 = e.x * r0, c1 = e.y * r1, c2 = e.z * r2, c3 = e.w * r3;
        ushort4 u = *(const ushort4*)(hbb + (size_t)s * HIDD + cq);
        float f0 = b2f(u.x), f1 = b2f(u.y), f2 = b2f(u.z), f3 = b2f(u.w);
        acc[0][0] += c0 * f0; acc[0][1] += c0 * f1; acc[0][2] += c0 * f2; acc[0][3] += c0 * f3;
        acc[1][0] += c1 * f0; acc[1][1] += c1 * f1; acc[1][2] += c1 * f2; acc[1][3] += c1 * f3;
        acc[2][0] += c2 * f0; acc[2][1] += c2 * f1; acc[2][2] += c2 * f2; acc[2][3] += c2 * f3;
        acc[3][0] += c3 * f0; acc[3][1] += c3 * f1; acc[3][2] += c3 * f2; acc[3][3] += c3 * f3;
    };
    if (deg <= MAXDEG) {
        int p = p0 + half;
        for (; p + 2 < p1; p += 4) {
            int s0 = srcp[p], s1 = srcp[p + 2];
            float4 e0 = exw[p - p0], e1 = exw[p + 2 - p0];
            doE(s0, e0);
            doE(s1, e1);
        }
        for (; p < p1; p += 2) doE(srcp[p], exw[p - p0]);
    } else {
        for (int p = p0 + half; p < p1; p += 2) {
            int s = srcp[p];
            int ix = p - p0;
            float4 e;
            if (ix < MAXDEG) e = exw[ix];
            else {
                int ty = etpp[p];
                float w = distwp[p];
                float4 a = ((const float4*)es)[s];
                float4 c = ((const float4*)etab)[ty];
                e.x = __expf(lrelu(a.x + edn.x + c.x, 0.2f)) * w;
                e.y = __expf(lrelu(a.y + edn.y + c.y, 0.2f)) * w;
                e.z = __expf(lrelu(a.z + edn.z + c.z, 0.2f)) * w;
                e.w = __expf(lrelu(a.w + edn.w + c.w, 0.2f)) * w;
            }
            doE(s, e);
        }
    }
    if (half == 1) {
#pragma unroll
        for (int h = 0; h < 4; ++h)
#pragma unroll
            for (int j = 0; j < 4; ++j) comb[q][h * 4 + j] = acc[h][j];
    }
    __syncthreads();
    if (half == 0) {
        b16* o = aggb + (size_t)n * 512;
#pragma unroll
        for (int h = 0; h < 4; ++h) {
            ushort4 w4;
            w4.x = f2b(acc[h][0] + comb[q][h * 4 + 0]);
            w4.y = f2b(acc[h][1] + comb[q][h * 4 + 1]);
            w4.z = f2b(acc[h][2] + comb[q][h * 4 + 2]);
            w4.w = f2b(acc[h][3] + comb[q][h * 4 + 3]);
            *(ushort4*)(o + h * 128 + cq) = w4;
        }
    }
}
// final: gather fp32 hL rows (36-wide), fused mean+bias+lrelu
__global__ __launch_bounds__(64) void k_aggL_f(
    const int* __restrict__ rowptr, const int* __restrict__ srcp,
    const int* __restrict__ etpp, const float* __restrict__ distwp,
    const float* __restrict__ es, const float* __restrict__ ed,
    const float* __restrict__ etab, const float* __restrict__ hL,
    const float* __restrict__ bL, float* __restrict__ out) {
    __shared__ float4 exw[MAXDEG];
    __shared__ float sh[40];
    int n = blockIdx.x, t = threadIdx.x;
    int p0 = rowptr[n], p1 = rowptr[n + 1];
    int deg = p1 - p0;
    float4 edn = ((const float4*)ed)[n];
    float d0 = 0.f, d1 = 0.f, d2 = 0.f, d3 = 0.f;
    for (int p = p0 + t; p < p1; p += 64) {
        int s = srcp[p], ty = etpp[p];
        float w = distwp[p];
        float4 a = ((const float4*)es)[s];
        float4 c = ((const float4*)etab)[ty];
        float e0 = __expf(lrelu(a.x + edn.x + c.x, 0.2f));
        float e1 = __expf(lrelu(a.y + edn.y + c.y, 0.2f));
        float e2 = __expf(lrelu(a.z + edn.z + c.z, 0.2f));
        float e3 = __expf(lrelu(a.w + edn.w + c.w, 0.2f));
        d0 += e0; d1 += e1; d2 += e2; d3 += e3;
        int ix = p - p0;
        if (ix < MAXDEG) exw[ix] = make_float4(e0 * w, e1 * w, e2 * w, e3 * w);
    }
#pragma unroll
    for (int off = 32; off > 0; off >>= 1) {
        d0 += __shfl_down(d0, off, 64);
        d1 += __shfl_down(d1, off, 64);
        d2 += __shfl_down(d2, off, 64);
        d3 += __shfl_down(d3, off, 64);
    }
    d0 = __shfl(d0, 0, 64); d1 = __shfl(d1, 0, 64);
    d2 = __shfl(d2, 0, 64); d3 = __shfl(d3, 0, 64);
    __syncthreads();
    if (t < 36) {
        int hh = t / 9;
        float rv = (hh == 0) ? 1.f / (d0 + 1e-16f)
                 : (hh == 1) ? 1.f / (d1 + 1e-16f)
                 : (hh == 2) ? 1.f / (d2 + 1e-16f)
                             : 1.f / (d3 + 1e-16f);
        float acc = 0.f;
        if (deg <= MAXDEG) {
            int p = p0;
            for (; p + 4 <= p1; p += 4) {
                int ss[4]; float aw[4];
#pragma unroll
                for (int j = 0; j < 4; ++j) {
                    ss[j] = srcp[p + j];
                    float4 e = exw[p - p0 + j];
                    aw[j] = (hh == 0) ? e.x : (hh == 1) ? e.y : (hh == 2) ? e.z : e.w;
                }
                float g[4];
#pragma unroll
                for (int j = 0; j < 4; ++j) g[j] = hL[(size_t)ss[j] * 36 + t];
#pragma unroll
                for (int j = 0; j < 4; ++j) acc += aw[j] * g[j];
            }
            for (; p < p1; ++p) {
                float4 e = exw[p - p0];
                float av = (hh == 0) ? e.x : (hh == 1) ? e.y : (hh == 2) ? e.z : e.w;
                acc += av * hL[(size_t)srcp[p] * 36 + t];
            }
        } else {
            for (int p = p0; p < p1; ++p) {
                int s = srcp[p];
                int ix = p - p0;
                float av;
                if (ix < MAXDEG) {
                    float4 e = exw[ix];
                    av = (hh == 0) ? e.x : (hh == 1) ? e.y : (hh == 2) ? e.z : e.w;
                } else {
                    int ty = etpp[p];
                    float w = distwp[p];
                    float4 a = ((const float4*)es)[s];
                    float4 c = ((const float4*)etab)[ty];
                    float lv = (hh == 0) ? a.x + edn.x + c.x
                             : (hh == 1) ? a.y + edn.y + c.y
                             : (hh == 2) ? a.z + edn.z + c.z
                                         : a.w + edn.w + c.w;
                    av = __expf(lrelu(lv, 0.2f)) * w;
                }
                acc += av * hL[(size_t)s * 36 + t];
            }
        }
        sh[t] = acc * rv;
    }
    __syncthreads();
    if (t < 9) {
        float v = 0.25f * (sh[t] + sh[t + 9] + sh[t + 18] + sh[t + 27]) + bL[t];
        out[(size_t)n * 9 + t] = lrelu(v, 0.1f);
    }
}

// ---------------- BN stats (layer 1 only; atomic into sums slot 0) ----------------
__global__ __launch_bounds__(128) void k_bnstats_at(const float* __restrict__ x,
                                                    float* __restrict__ sums) {
    int f = threadIdx.x;
    float s = 0.f, q = 0.f;
    for (int r = blockIdx.x; r < NN; r += 200) {
        float v = x[(size_t)r * HIDD + f];
        s += v;
        q += v * v;
    }
    atomicAdd(&sums[f], s);
    atomicAdd(&sums[128 + f], q);
}
// BN apply with inline scale/shift from sums + optional fused mid scores
__global__ __launch_bounds__(64) void k_bnaps(
    const float* __restrict__ x, const float* __restrict__ sums,
    const float* __restrict__ gamma, const float* __restrict__ beta,
    const float* __restrict__ Ws, const float* __restrict__ Wd,
    float* __restrict__ hb, b16* __restrict__ hbb,
    float* __restrict__ es, float* __restrict__ ed) {
    int n = blockIdx.x, t = threadIdx.x;
    int c0 = t * 2;
    float s0 = sums[c0], s1 = sums[c0 + 1];
    float q0 = sums[128 + c0], q1 = sums[128 + c0 + 1];
    float m0 = s0 * (1.f / NN), m1 = s1 * (1.f / NN);
    float v0 = q0 * (1.f / NN) - m0 * m0, v1 = q1 * (1.f / NN) - m1 * m1;
    float sc0 = gamma[c0] * rsqrtf(v0 + 1e-5f);
    float sc1 = gamma[c0 + 1] * rsqrtf(v1 + 1e-5f);
    float sh0 = beta[c0] - m0 * sc0, sh1 = beta[c0 + 1] - m1 * sc1;
    float2 xv = ((const float2*)(x + (size_t)n * HIDD))[t];
    float y0 = lrelu(xv.x * sc0 + sh0, 0.1f);
    float y1 = lrelu(xv.y * sc1 + sh1, 0.1f);
    ((float2*)(hb + (size_t)n * HIDD))[t] = make_float2(y0, y1);
    ushort2 ub; ub.x = f2b(y0); ub.y = f2b(y1);
    ((ushort2*)(hbb + (size_t)n * HIDD))[t] = ub;
    if (Ws) {
        float pe[4], pd[4];
#pragma unroll
        for (int h = 0; h < 4; ++h) {
            pe[h] = y0 * Ws[h * 128 + c0] + y1 * Ws[h * 128 + c0 + 1];
            pd[h] = y0 * Wd[h * 128 + c0] + y1 * Wd[h * 128 + c0 + 1];
        }
#pragma unroll
        for (int off = 32; off > 0; off >>= 1) {
#pragma unroll
            for (int h = 0; h < 4; ++h) {
                pe[h] += __shfl_down(pe[h], off, 64);
                pd[h] += __shfl_down(pd[h], off, 64);
            }
        }
        if (t == 0) {
#pragma unroll
            for (int h = 0; h < 4; ++h) {
                es[n * 4 + h] = pe[h];
                ed[n * 4 + h] = pd[h];
            }
        }
    }
}

extern "C" void kernel_launch(void* const* d_in, const int* in_sizes, int n_in,
                              void* d_out, int out_size, void* d_ws, size_t ws_size,
                              hipStream_t stream) {
    const float* x = (const float*)d_in[0];
    const int* ei = (const int*)d_in[1];
    const int* src = ei;
    const int* dst = ei + NE;
    const int* etype = (const int*)d_in[2];
    const int* edist = (const int*)d_in[3];
    const float* W0 = (const float*)d_in[4];
    const float* asrc0 = (const float*)d_in[5];
    const float* adst0 = (const float*)d_in[6];
    const float* aedge0 = (const float*)d_in[7];
    const float* b0 = (const float*)d_in[8];
    const float* rel0 = (const float*)d_in[9];
    const float* Wm = (const float*)d_in[10];
    const float* asrcm = (const float*)d_in[11];
    const float* adstm = (const float*)d_in[12];
    const float* aedgem = (const float*)d_in[13];
    const float* bm = (const float*)d_in[14];
    const float* relm = (const float*)d_in[15];
    const float* WL = (const float*)d_in[16];
    const float* asrcL = (const float*)d_in[17];
    const float* adstL = (const float*)d_in[18];
    const float* aedgeL = (const float*)d_in[19];
    const float* bL = (const float*)d_in[20];
    const float* relL = (const float*)d_in[21];
    const float* bng = (const float*)d_in[22];
    const float* bnb = (const float*)d_in[23];
    float* out = (float*)d_out;

    char* w = (char*)d_ws;
    size_t off = 0;
    auto alloc = [&](size_t bytes) -> char* {
        char* p = w + off;
        off = (off + bytes + 255) & ~(size_t)255;
        return p;
    };
    char* ws0 = alloc((size_t)NN * FIN * 2);             // xb bf16 during prep; then xbuf/hb/hL
    b16* xb = (b16*)ws0;
    float* xbuf = (float*)ws0;                           // [NN][128] fp32
    float* hb = (float*)(ws0 + 10240000);                // [NN][128] fp32
    float* hL = (float*)(ws0 + 20480000);                // [NN][36]  fp32
    b16* h0b = (b16*)alloc((size_t)NN * 512 * 2);        // h0 bf16 / agg bf16
    b16* B0t = (b16*)alloc((size_t)512 * FIN * 2);
    b16* Bmt = (b16*)alloc((size_t)3 * HIDD * 512 * 2);
    b16* WLt = (b16*)alloc((size_t)48 * HIDD * 2);
    b16* hbb = (b16*)alloc((size_t)NN * HIDD * 2);
    float* es = (float*)alloc((size_t)NN * 4 * 4);
    float* ed = (float*)alloc((size_t)NN * 4 * 4);
    int* srcp = (int*)alloc((size_t)NE * 4);
    int* etpp = (int*)alloc((size_t)NE * 4);
    float* distwp = (float*)alloc((size_t)NE * 4);
    int* eidx = (int*)alloc((size_t)NE * 4);
    float* sums = (float*)alloc(1024 * 4);               // 4 slots x 256
    float* wsmb = (float*)alloc(1536 * 4);
    float* wdmb = (float*)alloc(1536 * 4);
    float* etab = (float*)alloc(800 * 4);
    float* aS48 = (float*)alloc(48 * 4);
    float* aD48 = (float*)alloc(48 * 4);
    int* counts = (int*)alloc((size_t)NN * 4);
    int* rowptr = (int*)alloc((size_t)(NN + 1) * 4);
    int* cursor = (int*)alloc((size_t)(NN + 1) * 4);

    const int B256 = 256;
    int gNE = (NE + 255) / 256;
    int gNN = (NN + 255) / 256;

    // CSR + permutation + zero init
    k_init<<<gNN, B256, 0, stream>>>(counts, sums);
    k_count<<<gNE, B256, 0, stream>>>(dst, counts);
    k_scan<<<1, 1024, 0, stream>>>(counts, rowptr, cursor);
    k_fill<<<gNE, B256, 0, stream>>>(dst, cursor, eidx);
    k_permute<<<gNE, B256, 0, stream>>>(eidx, src, etype, edist, srcp, etpp, distwp);

    // fused casts + tables
    k_prep<<<(PREP_END + 255) / 256, B256, 0, stream>>>(
        x, W0, Wm, xb, B0t, Bmt,
        rel0, relm, relL, aedge0, aedgem, aedgeL, asrcm, adstm, WL, asrcL, adstL,
        etab, wsmb, wdmb, WLt, aS48, aD48);

    int mblk = (NN + 127) / 128;  // 157

    // ---- conv0 ----
    {
        dim3 g(mblk, 4);
        k_mfma_gemm<<<g, 256, 0, stream>>>(xb, B0t, NN, FIN, 512, h0b, asrc0, adst0, es, ed);
        k_agg0_f<<<NN, 64, 0, stream>>>(rowptr, srcp, etpp, distwp, es, ed, etab + 0,
                                        h0b, b0, xbuf);
        k_bnstats_at<<<200, 128, 0, stream>>>(xbuf, sums);  // slot 0
    }

    // ---- 3 middle convs ----
    int gmid = (NN + 63) / 64;  // 313
    for (int i = 0; i < 3; ++i) {
        k_bnaps<<<NN, 64, 0, stream>>>(xbuf, sums + i * 256, bng + i * 128, bnb + i * 128,
                                       wsmb + i * 512, wdmb + i * 512, hb, hbb, es, ed);
        k_aggmid_f<<<NN, 64, 0, stream>>>(rowptr, srcp, etpp, distwp, es, ed,
                                          etab + (1 + i) * 160, hbb, h0b);
        k_gemm_mid<<<gmid, 128, 0, stream>>>(h0b, Bmt + (size_t)i * HIDD * 512, xbuf,
                                             bm + i * 128, hb, sums + (i + 1) * 256);
    }

    // ---- final conv ----
    {
        k_bnaps<<<NN, 64, 0, stream>>>(xbuf, sums + 3 * 256, bng + 3 * 128, bnb + 3 * 128,
                                       nullptr, nullptr, hb, hbb, es, ed);
        k_gemmL_mfma<<<(NN + 63) / 64, 256, 0, stream>>>(hbb, WLt, hL, aS48, aD48, es, ed);
        k_aggL_f<<<NN, 64, 0, stream>>>(rowptr, srcp, etpp, distwp, es, ed, etab + 4 * 160,
                                        hL, bL, out);
    }
}